// Round 1
// baseline (737.251 us; speedup 1.0000x reference)
//
#include <hip/hip_runtime.h>
#include <math.h>

#define BATCH   8192
#define NOUTER  50
#define NINNER  15

// ---------------------------------------------------------------------------
// Per-branch pressure drop: dp = (Rduct*|q|^2 + Rl*|q|) + Rd*|q|^2
// (Rduct = exp(log_R_duct), Rl = |R_linear|, Rd = exp(log_R_open)*exp(k*(1-pos))
//  are constant per thread/branch and precomputed.)
// ---------------------------------------------------------------------------
__device__ __forceinline__ float branch_dp(float q, float Rduct, float Rl, float Rd) {
    float aq  = fabsf(q);
    float aq2 = aq * aq;
    return (Rduct * aq2 + Rl * aq) + Rd * aq2;
}

// 15-iteration flow distribution across 4 parallel branches.
__device__ __forceinline__ void distribute4(float total,
                                            const float Rduct[4], const float Rl[4], const float Rd[4],
                                            float fout[4], float pout[4]) {
    float f[4];
#pragma unroll
    for (int j = 0; j < 4; ++j) f[j] = total * 0.25f;

#pragma unroll 1
    for (int it = 0; it < NINNER; ++it) {
        float p[4], nw[4];
#pragma unroll
        for (int j = 0; j < 4; ++j) p[j] = branch_dp(f[j], Rduct[j], Rl[j], Rd[j]);
        float target = ((p[0] + p[1]) + (p[2] + p[3])) * 0.25f;
#pragma unroll
        for (int j = 0; j < 4; ++j) {
            float q2    = f[j] * f[j];
            float Req   = p[j] / (q2 + 1e-6f);
            float ratio = target / (Req + 1e-6f);
            nw[j] = sqrtf(fmaxf(ratio, 0.0f));
        }
        float s = ((nw[0] + nw[1]) + (nw[2] + nw[3]));
        float r = total / (s + 1e-6f);
#pragma unroll
        for (int j = 0; j < 4; ++j) f[j] = nw[j] * r;
    }
#pragma unroll
    for (int j = 0; j < 4; ++j) {
        fout[j] = f[j];
        pout[j] = branch_dp(f[j], Rduct[j], Rl[j], Rd[j]);
    }
}

__device__ __forceinline__ float fan_pressure(float flow, float speed, float a, float b, float c) {
    float fn = flow / (speed + 1e-6f);
    float pd = a * 1000.0f + b * fn + c * fn * fn;
    return fmaxf(pd * speed * speed, 0.0f);
}

__device__ __forceinline__ void load_branch_consts(int tid, const float* pos,
                                                   const float* lr, const float* rl,
                                                   const float* dlo, const float* dk,
                                                   float Rduct[4], float Rl[4], float Rd[4]) {
#pragma unroll
    for (int j = 0; j < 4; ++j) {
        Rduct[j] = expf(lr[j]);
        Rl[j]    = fabsf(rl[j]);
        Rd[j]    = expf(dlo[j]) * expf(dk[j] * (1.0f - pos[tid * 4 + j]));
    }
}

// ---------------------------------------------------------------------------
// Phase 1: run all 50 outer iterations ungated; record per-iteration global
// max|res| into slots[i] (atomicMax on float bits; |res|>=0 so signed-int
// compare is order-preserving and beats the 0xAA poison, which is negative).
// Also checkpoint flow after each update into hist[i*BATCH + tid].
// ---------------------------------------------------------------------------
__global__ __launch_bounds__(64) void phase1(
        const float* __restrict__ fan_speed,
        const float* __restrict__ sup_pos, const float* __restrict__ exh_pos,
        const float* __restrict__ pa, const float* __restrict__ pb, const float* __restrict__ pc,
        const float* __restrict__ slr, const float* __restrict__ srl,
        const float* __restrict__ sdo, const float* __restrict__ sdk,
        const float* __restrict__ elr, const float* __restrict__ erl,
        const float* __restrict__ edo, const float* __restrict__ edk,
        float* __restrict__ slots, float* __restrict__ hist, int use_hist) {
    int tid = blockIdx.x * blockDim.x + threadIdx.x;
    if (tid >= BATCH) return;

    float sRduct[4], sRl[4], sRd[4];
    float eRduct[4], eRl[4], eRd[4];
    load_branch_consts(tid, sup_pos, slr, srl, sdo, sdk, sRduct, sRl, sRd);
    load_branch_consts(tid, exh_pos, elr, erl, edo, edk, eRduct, eRl, eRd);

    float speed = fan_speed[tid];
    float a = pa[0], b = pb[0], c = pc[0];
    const float flow_scale = 2.0f / (500.0f + 1e-6f);

    float flow = speed * 2.0f;
    float alpha_base = 0.5f;

#pragma unroll 1
    for (int i = 0; i < NOUTER; ++i) {
        float ftmp[4], ptmp[4];
        distribute4(flow, sRduct, sRl, sRd, ftmp, ptmp);
        float sp0 = ptmp[0];
        distribute4(flow, eRduct, eRl, eRd, ftmp, ptmp);
        float ep0 = ptmp[0];

        float res  = fan_pressure(flow, speed, a, b, c) - (sp0 + ep0);
        float ares = fabsf(res);

        // wave-level max reduce (64 lanes), one atomic per wave
        float m = ares;
#pragma unroll
        for (int off = 32; off; off >>= 1) m = fmaxf(m, __shfl_xor(m, off));
        if ((threadIdx.x & 63) == 0)
            atomicMax((int*)&slots[i], __float_as_int(m));

        float alpha = fmaxf(alpha_base, 0.05f);
        alpha_base *= 0.95f;
        float fnew = flow + alpha * res * flow_scale;
        flow = fminf(fmaxf(fnew, 0.01f), 3.0f);
        if (use_hist) hist[(size_t)i * BATCH + tid] = flow;
    }
}

// ---------------------------------------------------------------------------
// Phase 2: replay the scalar stall/done automaton on the 50 err values.
// k = number of flow updates actually applied (iteration at which done first
// became true; 50 if never).
// ---------------------------------------------------------------------------
__global__ void phase2(const float* __restrict__ slots, int* __restrict__ kout) {
    float prev = INFINITY;
    int   stall = 0;
    int   k = NOUTER;
    bool  done = false;
#pragma unroll 1
    for (int i = 0; i < NOUTER; ++i) {
        float err = slots[i];
        bool stalled = fabsf(err - prev) < 1e-6f;
        stall = stalled ? stall + 1 : 0;
        done = done || (err < 1e-3f) || (stall > 10);
        if (done) { k = i; break; }
        prev = err;
    }
    *kout = k;
}

// ---------------------------------------------------------------------------
// Phase 3: recover flow after k updates (from history, or replay), then
// compute all outputs.  Layout per element: [flow, fan_p, sys_p, power,
// sf0..3, sp0..3, ef0..3, ep0..3]
// ---------------------------------------------------------------------------
template <bool USE_HIST>
__global__ __launch_bounds__(64) void phase3(
        const float* __restrict__ fan_speed,
        const float* __restrict__ sup_pos, const float* __restrict__ exh_pos,
        const float* __restrict__ pa, const float* __restrict__ pb, const float* __restrict__ pc,
        const float* __restrict__ slr, const float* __restrict__ srl,
        const float* __restrict__ sdo, const float* __restrict__ sdk,
        const float* __restrict__ elr, const float* __restrict__ erl,
        const float* __restrict__ edo, const float* __restrict__ edk,
        const float* __restrict__ hist, const int* __restrict__ kin,
        float* __restrict__ out) {
    int tid = blockIdx.x * blockDim.x + threadIdx.x;
    if (tid >= BATCH) return;
    int k = *kin;

    float sRduct[4], sRl[4], sRd[4];
    float eRduct[4], eRl[4], eRd[4];
    load_branch_consts(tid, sup_pos, slr, srl, sdo, sdk, sRduct, sRl, sRd);
    load_branch_consts(tid, exh_pos, elr, erl, edo, edk, eRduct, eRl, eRd);

    float speed = fan_speed[tid];
    float a = pa[0], b = pb[0], c = pc[0];
    const float flow_scale = 2.0f / (500.0f + 1e-6f);

    float flow;
    if (USE_HIST) {
        flow = (k == 0) ? speed * 2.0f : hist[(size_t)(k - 1) * BATCH + tid];
    } else {
        flow = speed * 2.0f;
        float alpha_base = 0.5f;
#pragma unroll 1
        for (int i = 0; i < k; ++i) {
            float ftmp[4], ptmp[4];
            distribute4(flow, sRduct, sRl, sRd, ftmp, ptmp);
            float sp0 = ptmp[0];
            distribute4(flow, eRduct, eRl, eRd, ftmp, ptmp);
            float ep0 = ptmp[0];
            float res = fan_pressure(flow, speed, a, b, c) - (sp0 + ep0);
            float alpha = fmaxf(alpha_base, 0.05f);
            alpha_base *= 0.95f;
            float fnew = flow + alpha * res * flow_scale;
            flow = fminf(fmaxf(fnew, 0.01f), 3.0f);
        }
    }

    flow = fmaxf(flow, 0.0f);
    float fanp = fan_pressure(flow, speed, a, b, c);

    float sf[4], sp[4], ef[4], ep[4];
    distribute4(flow, sRduct, sRl, sRd, sf, sp);
    distribute4(flow, eRduct, eRl, eRd, ef, ep);
    float sysp = sp[0] + ep[0];

    float fr  = flow / (2.0f + 1e-6f);
    float pr  = fanp / (500.0f + 1e-6f);
    float eta = 0.65f * (1.0f - 0.3f * (fr - 1.0f) * (fr - 1.0f)
                              - 0.2f * (pr - 1.0f) * (pr - 1.0f));
    eta = fminf(fmaxf(eta, 0.3f), 0.75f);
    float power = flow * fanp / (eta * 0.9f + 1e-6f);

    float* o = out + (size_t)tid * 20;
    o[0] = flow; o[1] = fanp; o[2] = sysp; o[3] = power;
#pragma unroll
    for (int j = 0; j < 4; ++j) {
        o[4 + j]  = sf[j];
        o[8 + j]  = sp[j];
        o[12 + j] = ef[j];
        o[16 + j] = ep[j];
    }
}

// ---------------------------------------------------------------------------
extern "C" void kernel_launch(void* const* d_in, const int* in_sizes, int n_in,
                              void* d_out, int out_size, void* d_ws, size_t ws_size,
                              hipStream_t stream) {
    const float* fan_speed = (const float*)d_in[0];
    const float* sup_pos   = (const float*)d_in[1];
    const float* exh_pos   = (const float*)d_in[2];
    const float* pa        = (const float*)d_in[3];
    const float* pb        = (const float*)d_in[4];
    const float* pc        = (const float*)d_in[5];
    const float* slr       = (const float*)d_in[6];
    const float* srl       = (const float*)d_in[7];
    const float* sdo       = (const float*)d_in[8];
    const float* sdk       = (const float*)d_in[9];
    const float* elr       = (const float*)d_in[10];
    const float* erl       = (const float*)d_in[11];
    const float* edo       = (const float*)d_in[12];
    const float* edk       = (const float*)d_in[13];

    float* ws    = (float*)d_ws;
    float* slots = ws;                 // 64 floats (50 used); poison is negative, atomicMax ok
    int*   kptr  = (int*)(ws + 64);    // 1 int
    float* hist  = ws + 128;           // BATCH*NOUTER floats (1.6 MB)

    size_t need_hist_bytes = (size_t)(128 + (size_t)BATCH * NOUTER) * sizeof(float);
    bool use_hist = ws_size >= need_hist_bytes;

    dim3 grid(BATCH / 64), block(64);

    phase1<<<grid, block, 0, stream>>>(fan_speed, sup_pos, exh_pos, pa, pb, pc,
                                       slr, srl, sdo, sdk, elr, erl, edo, edk,
                                       slots, hist, use_hist ? 1 : 0);
    phase2<<<1, 1, 0, stream>>>(slots, kptr);
    if (use_hist) {
        phase3<true><<<grid, block, 0, stream>>>(fan_speed, sup_pos, exh_pos, pa, pb, pc,
                                                 slr, srl, sdo, sdk, elr, erl, edo, edk,
                                                 hist, kptr, (float*)d_out);
    } else {
        phase3<false><<<grid, block, 0, stream>>>(fan_speed, sup_pos, exh_pos, pa, pb, pc,
                                                  slr, srl, sdo, sdk, elr, erl, edo, edk,
                                                  nullptr, kptr, (float*)d_out);
    }
}

// Round 2
// 434.120 us; speedup vs baseline: 1.6983x; 1.6983x over previous
//
#include <hip/hip_runtime.h>
#include <math.h>

#define BATCH   8192
#define NOUTER  50
#define NINNER  15
#define NTHREADS (BATCH * 8)   // 8 lanes per element: net(2) x branch(4)

__device__ __forceinline__ float fast_rcp(float x)  { return __builtin_amdgcn_rcpf(x); }
__device__ __forceinline__ float fast_sqrt(float x) { return __builtin_amdgcn_sqrtf(x); }

// ---------------------------------------------------------------------------
// Lane-parallel flow distribution. Each lane owns ONE branch. Cross-branch
// sums via shfl_xor(1), shfl_xor(2) within the 4-lane branch group.
// dp = (Rduct+Rd)*q^2 + Rl*|q| = fma(R2, q*q, Rl*|q|)
// ratio = target/(Req+1e-6) with Req = p/(q2e)  ==  target*q2e/(p + 1e-6*q2e)
// ---------------------------------------------------------------------------
__device__ __forceinline__ float distribute_lane(float total, float R2, float Rl,
                                                 float& pout) {
    float f = total * 0.25f;
#pragma unroll
    for (int it = 0; it < NINNER; ++it) {
        float aq = fabsf(f);
        float p  = fmaf(R2, f * f, Rl * aq);
        float t  = p + __shfl_xor(p, 1);
        t       += __shfl_xor(t, 2);
        float target = t * 0.25f;
        float q2e = fmaf(f, f, 1e-6f);
        float den = fmaf(q2e, 1e-6f, p);
        float ratio = target * q2e * fast_rcp(den);
        float nw = fast_sqrt(fmaxf(ratio, 0.0f));
        float s  = nw + __shfl_xor(nw, 1);
        s       += __shfl_xor(s, 2);
        f = nw * total * fast_rcp(s + 1e-6f);
    }
    float aq = fabsf(f);
    pout = fmaf(R2, f * f, Rl * aq);
    return f;
}

__device__ __forceinline__ float fan_pressure(float flow, float rspeed, float speed2,
                                              float a1000, float b, float c) {
    float fn = flow * rspeed;
    float pd = fmaf(c, fn * fn, fmaf(b, fn, a1000));
    return fmaxf(pd * speed2, 0.0f);
}

// sys pressure = p0(sup) + p0(exh), broadcast to all 8 lanes of the element.
__device__ __forceinline__ float sys_from_p(float pfin, int lane) {
    float p0 = __shfl(pfin, lane & ~3);    // branch-0 value of own network
    return p0 + __shfl_xor(p0, 4);          // + other network's p0 (commutative)
}

struct LaneConsts {
    float R2, Rl;            // own branch
    float speed, rspeed, speed2, a1000, b, c;
    int elem, lane, sub;
};

__device__ __forceinline__ LaneConsts setup_lane(
        const float* fan_speed,
        const float* sup_pos, const float* exh_pos,
        const float* pa, const float* pb, const float* pc,
        const float* slr, const float* srl, const float* sdo, const float* sdk,
        const float* elr, const float* erl, const float* edo, const float* edk) {
    LaneConsts L;
    int t   = blockIdx.x * blockDim.x + threadIdx.x;
    L.elem  = t >> 3;
    L.sub   = t & 7;
    int net = (L.sub >> 2) & 1;
    int j   = L.sub & 3;
    L.lane  = threadIdx.x & 63;

    const float* pos = net ? exh_pos : sup_pos;
    const float* lr  = net ? elr : slr;
    const float* rl  = net ? erl : srl;
    const float* dlo = net ? edo : sdo;
    const float* dk  = net ? edk : sdk;

    float Rduct = expf(lr[j]);
    float Rd    = expf(dlo[j]) * expf(dk[j] * (1.0f - pos[L.elem * 4 + j]));
    L.R2 = Rduct + Rd;
    L.Rl = fabsf(rl[j]);

    L.speed  = fan_speed[L.elem];
    L.rspeed = fast_rcp(L.speed + 1e-6f);
    L.speed2 = L.speed * L.speed;
    L.a1000  = pa[0] * 1000.0f;
    L.b      = pb[0];
    L.c      = pc[0];
    return L;
}

// ---------------------------------------------------------------------------
// Phase 1: run all 50 outer iterations ungated; record per-iteration global
// max|res| via atomicMax on float bits (|res|>=0, poison 0xAA.. is negative).
// Checkpoint flow after each update.
// ---------------------------------------------------------------------------
__global__ __launch_bounds__(256) void phase1(
        const float* __restrict__ fan_speed,
        const float* __restrict__ sup_pos, const float* __restrict__ exh_pos,
        const float* __restrict__ pa, const float* __restrict__ pb, const float* __restrict__ pc,
        const float* __restrict__ slr, const float* __restrict__ srl,
        const float* __restrict__ sdo, const float* __restrict__ sdk,
        const float* __restrict__ elr, const float* __restrict__ erl,
        const float* __restrict__ edo, const float* __restrict__ edk,
        float* __restrict__ slots, float* __restrict__ hist, int use_hist) {
    LaneConsts L = setup_lane(fan_speed, sup_pos, exh_pos, pa, pb, pc,
                              slr, srl, sdo, sdk, elr, erl, edo, edk);
    const float flow_scale = 2.0f / (500.0f + 1e-6f);
    float flow = L.speed * 2.0f;
    float alpha_base = 0.5f;

#pragma unroll 1
    for (int i = 0; i < NOUTER; ++i) {
        float pfin;
        (void)distribute_lane(flow, L.R2, L.Rl, pfin);
        float sys  = sys_from_p(pfin, L.lane);
        float res  = fan_pressure(flow, L.rspeed, L.speed2, L.a1000, L.b, L.c) - sys;
        float ares = fabsf(res);

        // all 8 lanes of an element hold the same ares -> reduce masks 8,16,32
        float m = ares;
        m = fmaxf(m, __shfl_xor(m, 8));
        m = fmaxf(m, __shfl_xor(m, 16));
        m = fmaxf(m, __shfl_xor(m, 32));
        if (L.lane == 0)
            atomicMax((int*)&slots[i], __float_as_int(m));

        float alpha = fmaxf(alpha_base, 0.05f);
        alpha_base *= 0.95f;
        float fnew = fmaf(alpha * res, flow_scale, flow);
        flow = fminf(fmaxf(fnew, 0.01f), 3.0f);
        if (use_hist && L.sub == 0) hist[(size_t)i * BATCH + L.elem] = flow;
    }
}

// ---------------------------------------------------------------------------
// Phase 2+3 fused: every thread replays the scalar stall/done automaton on the
// 50 recorded errs (uniform scalar loads, L2-hot), recovers flow after k
// updates, computes outputs.
// Output layout per element: [flow, fan_p, sys_p, power, sf0..3, sp0..3,
//                             ef0..3, ep0..3]
// ---------------------------------------------------------------------------
template <bool USE_HIST>
__global__ __launch_bounds__(256) void phase3(
        const float* __restrict__ fan_speed,
        const float* __restrict__ sup_pos, const float* __restrict__ exh_pos,
        const float* __restrict__ pa, const float* __restrict__ pb, const float* __restrict__ pc,
        const float* __restrict__ slr, const float* __restrict__ srl,
        const float* __restrict__ sdo, const float* __restrict__ sdk,
        const float* __restrict__ elr, const float* __restrict__ erl,
        const float* __restrict__ edo, const float* __restrict__ edk,
        const float* __restrict__ slots, const float* __restrict__ hist,
        float* __restrict__ out) {
    LaneConsts L = setup_lane(fan_speed, sup_pos, exh_pos, pa, pb, pc,
                              slr, srl, sdo, sdk, elr, erl, edo, edk);

    // ---- automaton replay (uniform across all threads) ----
    float prev = INFINITY;
    int stall = 0, k = NOUTER;
    bool done = false;
#pragma unroll 1
    for (int i = 0; i < NOUTER; ++i) {
        float err = slots[i];
        bool stalled = fabsf(err - prev) < 1e-6f;
        stall = stalled ? stall + 1 : 0;
        done = done || (err < 1e-3f) || (stall > 10);
        if (done) { k = i; break; }
        prev = err;
    }

    const float flow_scale = 2.0f / (500.0f + 1e-6f);
    float flow;
    if (USE_HIST) {
        flow = (k == 0) ? L.speed * 2.0f : hist[(size_t)(k - 1) * BATCH + L.elem];
    } else {
        flow = L.speed * 2.0f;
        float alpha_base = 0.5f;
#pragma unroll 1
        for (int i = 0; i < k; ++i) {
            float pfin;
            (void)distribute_lane(flow, L.R2, L.Rl, pfin);
            float sys = sys_from_p(pfin, L.lane);
            float res = fan_pressure(flow, L.rspeed, L.speed2, L.a1000, L.b, L.c) - sys;
            float alpha = fmaxf(alpha_base, 0.05f);
            alpha_base *= 0.95f;
            float fnew = fmaf(alpha * res, flow_scale, flow);
            flow = fminf(fmaxf(fnew, 0.01f), 3.0f);
        }
    }

    flow = fmaxf(flow, 0.0f);
    float fanp = fan_pressure(flow, L.rspeed, L.speed2, L.a1000, L.b, L.c);

    float pfin;
    float ffin = distribute_lane(flow, L.R2, L.Rl, pfin);
    float sys  = sys_from_p(pfin, L.lane);

    float fr  = flow * (1.0f / (2.0f + 1e-6f));
    float pr  = fanp * (1.0f / (500.0f + 1e-6f));
    float eta = 0.65f * (1.0f - 0.3f * (fr - 1.0f) * (fr - 1.0f)
                              - 0.2f * (pr - 1.0f) * (pr - 1.0f));
    eta = fminf(fmaxf(eta, 0.3f), 0.75f);
    float power = flow * fanp * fast_rcp(eta * 0.9f + 1e-6f);

    float* o = out + (size_t)L.elem * 20;
    if (L.sub == 0) {
        o[0] = flow; o[1] = fanp; o[2] = sys; o[3] = power;
    }
    int net = (L.sub >> 2) & 1;
    int j   = L.sub & 3;
    o[4 + net * 8 + j] = ffin;
    o[8 + net * 8 + j] = pfin;
}

// ---------------------------------------------------------------------------
extern "C" void kernel_launch(void* const* d_in, const int* in_sizes, int n_in,
                              void* d_out, int out_size, void* d_ws, size_t ws_size,
                              hipStream_t stream) {
    const float* fan_speed = (const float*)d_in[0];
    const float* sup_pos   = (const float*)d_in[1];
    const float* exh_pos   = (const float*)d_in[2];
    const float* pa        = (const float*)d_in[3];
    const float* pb        = (const float*)d_in[4];
    const float* pc        = (const float*)d_in[5];
    const float* slr       = (const float*)d_in[6];
    const float* srl       = (const float*)d_in[7];
    const float* sdo       = (const float*)d_in[8];
    const float* sdk       = (const float*)d_in[9];
    const float* elr       = (const float*)d_in[10];
    const float* erl       = (const float*)d_in[11];
    const float* edo       = (const float*)d_in[12];
    const float* edk       = (const float*)d_in[13];

    float* ws    = (float*)d_ws;
    float* slots = ws;            // 64 floats (50 used)
    float* hist  = ws + 64;       // BATCH*NOUTER floats (1.6 MB)

    size_t need_hist_bytes = (size_t)(64 + (size_t)BATCH * NOUTER) * sizeof(float);
    bool use_hist = ws_size >= need_hist_bytes;

    dim3 grid(NTHREADS / 256), block(256);

    phase1<<<grid, block, 0, stream>>>(fan_speed, sup_pos, exh_pos, pa, pb, pc,
                                       slr, srl, sdo, sdk, elr, erl, edo, edk,
                                       slots, hist, use_hist ? 1 : 0);
    if (use_hist) {
        phase3<true><<<grid, block, 0, stream>>>(fan_speed, sup_pos, exh_pos, pa, pb, pc,
                                                 slr, srl, sdo, sdk, elr, erl, edo, edk,
                                                 slots, hist, (float*)d_out);
    } else {
        phase3<false><<<grid, block, 0, stream>>>(fan_speed, sup_pos, exh_pos, pa, pb, pc,
                                                  slr, srl, sdo, sdk, elr, erl, edo, edk,
                                                  slots, nullptr, (float*)d_out);
    }
}

// Round 3
// 433.895 us; speedup vs baseline: 1.6991x; 1.0005x over previous
//
#include <hip/hip_runtime.h>
#include <math.h>

#define BATCH   8192
#define NOUTER  50
#define NINNER  15
#define NTHREADS (BATCH * 8)   // 8 lanes per element: net(2) x branch(4)

__device__ __forceinline__ float fast_rcp(float x)  { return __builtin_amdgcn_rcpf(x); }
__device__ __forceinline__ float fast_sqrt(float x) { return __builtin_amdgcn_sqrtf(x); }

// DPP cross-lane move (VALU pipe, ~2-4 cyc — replaces ds_bpermute ~120 cyc).
// CTRL: quad_perm = sel0|sel1<<2|sel2<<4|sel3<<6; 0x128=row_ror:8; 0x141=row_half_mirror
template <int CTRL>
__device__ __forceinline__ float dpp_movf(float x) {
    return __int_as_float(__builtin_amdgcn_update_dpp(
        0, __float_as_int(x), CTRL, 0xF, 0xF, true));
}
#define DPP_XOR1  0xB1   // quad_perm [1,0,3,2]
#define DPP_XOR2  0x4E   // quad_perm [2,3,0,1]
#define DPP_BQ0   0x00   // quad_perm [0,0,0,0] : broadcast quad lane 0
#define DPP_ROR8  0x128  // row_ror:8  == xor8 within 16-lane row
#define DPP_HMIR  0x141  // row_half_mirror == xor7 (== xor4 on quad-uniform data)

// ---------------------------------------------------------------------------
// Lane-parallel flow distribution. Each lane owns ONE branch. Cross-branch
// sums via quad_perm DPP. Arithmetic identical to previous round (bit-exact).
// dp = (Rduct+Rd)*q^2 + Rl*|q| = fma(R2, q*q, Rl*|q|)
// ratio = target/(Req+1e-6), Req = p/q2e  ==  target*q2e/(p + 1e-6*q2e)
// ---------------------------------------------------------------------------
__device__ __forceinline__ float distribute_lane(float total, float R2, float Rl,
                                                 float& pout) {
    float f = total * 0.25f;
#pragma unroll
    for (int it = 0; it < NINNER; ++it) {
        float aq = fabsf(f);
        float p  = fmaf(R2, f * f, Rl * aq);
        float t  = p + dpp_movf<DPP_XOR1>(p);
        t       += dpp_movf<DPP_XOR2>(t);
        float target = t * 0.25f;
        float q2e = fmaf(f, f, 1e-6f);
        float den = fmaf(q2e, 1e-6f, p);
        float ratio = target * q2e * fast_rcp(den);
        float nw = fast_sqrt(fmaxf(ratio, 0.0f));
        float s  = nw + dpp_movf<DPP_XOR1>(nw);
        s       += dpp_movf<DPP_XOR2>(s);
        f = nw * total * fast_rcp(s + 1e-6f);
    }
    float aq = fabsf(f);
    pout = fmaf(R2, f * f, Rl * aq);
    return f;
}

__device__ __forceinline__ float fan_pressure(float flow, float rspeed, float speed2,
                                              float a1000, float b, float c) {
    float fn = flow * rspeed;
    float pd = fmaf(c, fn * fn, fmaf(b, fn, a1000));
    return fmaxf(pd * speed2, 0.0f);
}

// sys pressure = p0(sup) + p0(exh), broadcast to all 8 lanes of the element.
// p0 is quad-uniform after the quad-lane-0 broadcast, so row_half_mirror
// (xor7) delivers the other network's p0.
__device__ __forceinline__ float sys_from_p(float pfin) {
    float p0 = dpp_movf<DPP_BQ0>(pfin);
    return p0 + dpp_movf<DPP_HMIR>(p0);
}

struct LaneConsts {
    float R2, Rl;            // own branch
    float speed, rspeed, speed2, a1000, b, c;
    int elem, lane, sub;
};

__device__ __forceinline__ LaneConsts setup_lane(
        const float* fan_speed,
        const float* sup_pos, const float* exh_pos,
        const float* pa, const float* pb, const float* pc,
        const float* slr, const float* srl, const float* sdo, const float* sdk,
        const float* elr, const float* erl, const float* edo, const float* edk) {
    LaneConsts L;
    int t   = blockIdx.x * blockDim.x + threadIdx.x;
    L.elem  = t >> 3;
    L.sub   = t & 7;
    int net = (L.sub >> 2) & 1;
    int j   = L.sub & 3;
    L.lane  = threadIdx.x & 63;

    const float* pos = net ? exh_pos : sup_pos;
    const float* lr  = net ? elr : slr;
    const float* rl  = net ? erl : srl;
    const float* dlo = net ? edo : sdo;
    const float* dk  = net ? edk : sdk;

    float Rduct = expf(lr[j]);
    float Rd    = expf(dlo[j]) * expf(dk[j] * (1.0f - pos[L.elem * 4 + j]));
    L.R2 = Rduct + Rd;
    L.Rl = fabsf(rl[j]);

    L.speed  = fan_speed[L.elem];
    L.rspeed = fast_rcp(L.speed + 1e-6f);
    L.speed2 = L.speed * L.speed;
    L.a1000  = pa[0] * 1000.0f;
    L.b      = pb[0];
    L.c      = pc[0];
    return L;
}

// ---------------------------------------------------------------------------
// Phase 1: all 50 outer iterations ungated; record per-iteration global
// max|res| via atomicMax on float bits (|res|>=0; 0xAA.. poison is negative).
// Checkpoint flow after each update.
// ---------------------------------------------------------------------------
__global__ __launch_bounds__(256) void phase1(
        const float* __restrict__ fan_speed,
        const float* __restrict__ sup_pos, const float* __restrict__ exh_pos,
        const float* __restrict__ pa, const float* __restrict__ pb, const float* __restrict__ pc,
        const float* __restrict__ slr, const float* __restrict__ srl,
        const float* __restrict__ sdo, const float* __restrict__ sdk,
        const float* __restrict__ elr, const float* __restrict__ erl,
        const float* __restrict__ edo, const float* __restrict__ edk,
        float* __restrict__ slots, float* __restrict__ hist, int use_hist) {
    LaneConsts L = setup_lane(fan_speed, sup_pos, exh_pos, pa, pb, pc,
                              slr, srl, sdo, sdk, elr, erl, edo, edk);
    const float flow_scale = 2.0f / (500.0f + 1e-6f);
    float flow = L.speed * 2.0f;
    float alpha_base = 0.5f;

#pragma unroll 1
    for (int i = 0; i < NOUTER; ++i) {
        float pfin;
        (void)distribute_lane(flow, L.R2, L.Rl, pfin);
        float sys  = sys_from_p(pfin);
        float res  = fan_pressure(flow, L.rspeed, L.speed2, L.a1000, L.b, L.c) - sys;
        float ares = fabsf(res);

        // wave max-reduce: ares uniform across 8 lanes/element -> masks 8,16,32
        float m = ares;
        m = fmaxf(m, dpp_movf<DPP_ROR8>(m));   // xor8 (VALU)
        m = fmaxf(m, __shfl_xor(m, 16));       // once per outer iter; DS ok
        m = fmaxf(m, __shfl_xor(m, 32));
        if (L.lane == 0)
            atomicMax((int*)&slots[i], __float_as_int(m));

        float alpha = fmaxf(alpha_base, 0.05f);
        alpha_base *= 0.95f;
        float fnew = fmaf(alpha * res, flow_scale, flow);
        flow = fminf(fmaxf(fnew, 0.01f), 3.0f);
        if (use_hist && L.sub == 0) hist[(size_t)i * BATCH + L.elem] = flow;
    }
}

// ---------------------------------------------------------------------------
// Phase 2+3 fused: replay the scalar stall/done automaton on the 50 recorded
// errs, recover flow after k updates, compute outputs.
// Output layout per element: [flow, fan_p, sys_p, power, sf0..3, sp0..3,
//                             ef0..3, ep0..3]
// ---------------------------------------------------------------------------
template <bool USE_HIST>
__global__ __launch_bounds__(256) void phase3(
        const float* __restrict__ fan_speed,
        const float* __restrict__ sup_pos, const float* __restrict__ exh_pos,
        const float* __restrict__ pa, const float* __restrict__ pb, const float* __restrict__ pc,
        const float* __restrict__ slr, const float* __restrict__ srl,
        const float* __restrict__ sdo, const float* __restrict__ sdk,
        const float* __restrict__ elr, const float* __restrict__ erl,
        const float* __restrict__ edo, const float* __restrict__ edk,
        const float* __restrict__ slots, const float* __restrict__ hist,
        float* __restrict__ out) {
    LaneConsts L = setup_lane(fan_speed, sup_pos, exh_pos, pa, pb, pc,
                              slr, srl, sdo, sdk, elr, erl, edo, edk);

    // ---- automaton replay (uniform across all threads, L2-hot) ----
    float prev = INFINITY;
    int stall = 0, k = NOUTER;
    bool done = false;
#pragma unroll 1
    for (int i = 0; i < NOUTER; ++i) {
        float err = slots[i];
        bool stalled = fabsf(err - prev) < 1e-6f;
        stall = stalled ? stall + 1 : 0;
        done = done || (err < 1e-3f) || (stall > 10);
        if (done) { k = i; break; }
        prev = err;
    }

    const float flow_scale = 2.0f / (500.0f + 1e-6f);
    float flow;
    if (USE_HIST) {
        flow = (k == 0) ? L.speed * 2.0f : hist[(size_t)(k - 1) * BATCH + L.elem];
    } else {
        flow = L.speed * 2.0f;
        float alpha_base = 0.5f;
#pragma unroll 1
        for (int i = 0; i < k; ++i) {
            float pfin;
            (void)distribute_lane(flow, L.R2, L.Rl, pfin);
            float sys = sys_from_p(pfin);
            float res = fan_pressure(flow, L.rspeed, L.speed2, L.a1000, L.b, L.c) - sys;
            float alpha = fmaxf(alpha_base, 0.05f);
            alpha_base *= 0.95f;
            float fnew = fmaf(alpha * res, flow_scale, flow);
            flow = fminf(fmaxf(fnew, 0.01f), 3.0f);
        }
    }

    flow = fmaxf(flow, 0.0f);
    float fanp = fan_pressure(flow, L.rspeed, L.speed2, L.a1000, L.b, L.c);

    float pfin;
    float ffin = distribute_lane(flow, L.R2, L.Rl, pfin);
    float sys  = sys_from_p(pfin);

    float fr  = flow * (1.0f / (2.0f + 1e-6f));
    float pr  = fanp * (1.0f / (500.0f + 1e-6f));
    float eta = 0.65f * (1.0f - 0.3f * (fr - 1.0f) * (fr - 1.0f)
                              - 0.2f * (pr - 1.0f) * (pr - 1.0f));
    eta = fminf(fmaxf(eta, 0.3f), 0.75f);
    float power = flow * fanp * fast_rcp(eta * 0.9f + 1e-6f);

    float* o = out + (size_t)L.elem * 20;
    if (L.sub == 0) {
        o[0] = flow; o[1] = fanp; o[2] = sys; o[3] = power;
    }
    int net = (L.sub >> 2) & 1;
    int j   = L.sub & 3;
    o[4 + net * 8 + j] = ffin;
    o[8 + net * 8 + j] = pfin;
}

// ---------------------------------------------------------------------------
extern "C" void kernel_launch(void* const* d_in, const int* in_sizes, int n_in,
                              void* d_out, int out_size, void* d_ws, size_t ws_size,
                              hipStream_t stream) {
    const float* fan_speed = (const float*)d_in[0];
    const float* sup_pos   = (const float*)d_in[1];
    const float* exh_pos   = (const float*)d_in[2];
    const float* pa        = (const float*)d_in[3];
    const float* pb        = (const float*)d_in[4];
    const float* pc        = (const float*)d_in[5];
    const float* slr       = (const float*)d_in[6];
    const float* srl       = (const float*)d_in[7];
    const float* sdo       = (const float*)d_in[8];
    const float* sdk       = (const float*)d_in[9];
    const float* elr       = (const float*)d_in[10];
    const float* erl       = (const float*)d_in[11];
    const float* edo       = (const float*)d_in[12];
    const float* edk       = (const float*)d_in[13];

    float* ws    = (float*)d_ws;
    float* slots = ws;            // 64 floats (50 used)
    float* hist  = ws + 64;       // BATCH*NOUTER floats (1.6 MB)

    size_t need_hist_bytes = (size_t)(64 + (size_t)BATCH * NOUTER) * sizeof(float);
    bool use_hist = ws_size >= need_hist_bytes;

    dim3 grid(NTHREADS / 256), block(256);

    phase1<<<grid, block, 0, stream>>>(fan_speed, sup_pos, exh_pos, pa, pb, pc,
                                       slr, srl, sdo, sdk, elr, erl, edo, edk,
                                       slots, hist, use_hist ? 1 : 0);
    if (use_hist) {
        phase3<true><<<grid, block, 0, stream>>>(fan_speed, sup_pos, exh_pos, pa, pb, pc,
                                                 slr, srl, sdo, sdk, elr, erl, edo, edk,
                                                 slots, hist, (float*)d_out);
    } else {
        phase3<false><<<grid, block, 0, stream>>>(fan_speed, sup_pos, exh_pos, pa, pb, pc,
                                                  slr, srl, sdo, sdk, elr, erl, edo, edk,
                                                  slots, nullptr, (float*)d_out);
    }
}

// Round 5
// 138.085 us; speedup vs baseline: 5.3391x; 3.1422x over previous
//
#include <hip/hip_runtime.h>
#include <math.h>

#define BATCH   8192
#define NOUTER  50
#define NINNER  15
#define NTHREADS (BATCH * 8)   // 8 lanes per element: net(2) x branch(4)

__device__ __forceinline__ float fast_rcp(float x)  { return __builtin_amdgcn_rcpf(x); }
__device__ __forceinline__ float fast_sqrt(float x) { return __builtin_amdgcn_sqrtf(x); }

// DPP cross-lane move (VALU pipe). quad_perm = sel0|sel1<<2|sel2<<4|sel3<<6
template <int CTRL>
__device__ __forceinline__ float dpp_movf(float x) {
    return __int_as_float(__builtin_amdgcn_update_dpp(
        0, __float_as_int(x), CTRL, 0xF, 0xF, true));
}
#define DPP_XOR1  0xB1   // quad_perm [1,0,3,2]
#define DPP_XOR2  0x4E   // quad_perm [2,3,0,1]
#define DPP_BQ0   0x00   // quad_perm [0,0,0,0] : broadcast quad lane 0
#define DPP_ROR8  0x128  // row_ror:8  == xor8 within 16-lane row (on 8-uniform data)
#define DPP_HMIR  0x141  // row_half_mirror == xor7 (== xor4 on quad-uniform data)

// ---------------------------------------------------------------------------
// Lane-parallel flow distribution. Each lane owns ONE branch. Cross-branch
// sums via quad_perm DPP. Value path BIT-IDENTICAL to round 2 (the removed
// fabsf/fmaxf are identities: f >= 0 and ratio >= 0 are provable invariants).
// ---------------------------------------------------------------------------
__device__ __forceinline__ float distribute_lane(float total, float R2, float Rl,
                                                 float& pout) {
    float f = total * 0.25f;
#pragma unroll
    for (int it = 0; it < NINNER; ++it) {
        float p  = fmaf(R2, f * f, Rl * f);          // f >= 0 -> |f| == f
        float t  = p + dpp_movf<DPP_XOR1>(p);
        t       += dpp_movf<DPP_XOR2>(t);
        float target = t * 0.25f;
        float q2e = fmaf(f, f, 1e-6f);
        float den = fmaf(q2e, 1e-6f, p);
        float ratio = target * q2e * fast_rcp(den);  // >= 0 by construction
        float nw = fast_sqrt(ratio);
        float s  = nw + dpp_movf<DPP_XOR1>(nw);
        s       += dpp_movf<DPP_XOR2>(s);
        f = nw * total * fast_rcp(s + 1e-6f);
    }
    pout = fmaf(R2, f * f, Rl * f);
    return f;
}

__device__ __forceinline__ float fan_pressure(float flow, float rspeed, float speed2,
                                              float a1000, float b, float c) {
    float fn = flow * rspeed;
    float pd = fmaf(c, fn * fn, fmaf(b, fn, a1000));
    return fmaxf(pd * speed2, 0.0f);
}

// sys pressure = p0(sup) + p0(exh), broadcast to all 8 lanes of the element.
__device__ __forceinline__ float sys_from_p(float pfin) {
    float p0 = dpp_movf<DPP_BQ0>(pfin);
    return p0 + dpp_movf<DPP_HMIR>(p0);
}

struct LaneConsts {
    float R2, Rl;
    float speed, rspeed, speed2, a1000, b, c;
    int elem, lane, sub;
};

__device__ __forceinline__ LaneConsts setup_lane(
        const float* fan_speed,
        const float* sup_pos, const float* exh_pos,
        const float* pa, const float* pb, const float* pc,
        const float* slr, const float* srl, const float* sdo, const float* sdk,
        const float* elr, const float* erl, const float* edo, const float* edk) {
    LaneConsts L;
    int t   = blockIdx.x * blockDim.x + threadIdx.x;
    L.elem  = t >> 3;
    L.sub   = t & 7;
    int net = (L.sub >> 2) & 1;
    int j   = L.sub & 3;
    L.lane  = threadIdx.x & 63;

    const float* pos = net ? exh_pos : sup_pos;
    const float* lr  = net ? elr : slr;
    const float* rl  = net ? erl : srl;
    const float* dlo = net ? edo : sdo;
    const float* dk  = net ? edk : sdk;

    float Rduct = expf(lr[j]);
    float Rd    = expf(dlo[j]) * expf(dk[j] * (1.0f - pos[L.elem * 4 + j]));
    L.R2 = Rduct + Rd;
    L.Rl = fabsf(rl[j]);

    L.speed  = fan_speed[L.elem];
    L.rspeed = fast_rcp(L.speed + 1e-6f);
    L.speed2 = L.speed * L.speed;
    L.a1000  = pa[0] * 1000.0f;
    L.b      = pb[0];
    L.c      = pc[0];
    return L;
}

// ---------------------------------------------------------------------------
// Phase 1: all 50 outer iterations ungated.
//   stage != nullptr : store |res| per lane (coalesced, fire-and-forget,
//                      OFF the dependency chain) -> phase1b reduces.
//                      NO atomics, NO DS ops anywhere in the hot loop.
//   stage == nullptr : fallback: wave max-reduce + atomicMax (round-2 path).
// ---------------------------------------------------------------------------
__global__ __launch_bounds__(256) void phase1(
        const float* __restrict__ fan_speed,
        const float* __restrict__ sup_pos, const float* __restrict__ exh_pos,
        const float* __restrict__ pa, const float* __restrict__ pb, const float* __restrict__ pc,
        const float* __restrict__ slr, const float* __restrict__ srl,
        const float* __restrict__ sdo, const float* __restrict__ sdk,
        const float* __restrict__ elr, const float* __restrict__ erl,
        const float* __restrict__ edo, const float* __restrict__ edk,
        float* __restrict__ slots, float* __restrict__ hist,
        float* __restrict__ stage, int use_hist) {
    LaneConsts L = setup_lane(fan_speed, sup_pos, exh_pos, pa, pb, pc,
                              slr, srl, sdo, sdk, elr, erl, edo, edk);
    int t = blockIdx.x * blockDim.x + threadIdx.x;
    const float flow_scale = 2.0f / (500.0f + 1e-6f);
    float flow = L.speed * 2.0f;
    float alpha_base = 0.5f;

#pragma unroll 1
    for (int i = 0; i < NOUTER; ++i) {
        float pfin;
        (void)distribute_lane(flow, L.R2, L.Rl, pfin);
        float sys  = sys_from_p(pfin);
        float res  = fan_pressure(flow, L.rspeed, L.speed2, L.a1000, L.b, L.c) - sys;
        float ares = fabsf(res);

        if (stage) {
            stage[(size_t)i * NTHREADS + t] = ares;   // coalesced, not on chain
        } else {
            float m = ares;
            m = fmaxf(m, dpp_movf<DPP_ROR8>(m));
            m = fmaxf(m, __shfl_xor(m, 16));
            m = fmaxf(m, __shfl_xor(m, 32));
            if (L.lane == 0)
                atomicMax((int*)&slots[i], __float_as_int(m));
        }

        float alpha = fmaxf(alpha_base, 0.05f);
        alpha_base *= 0.95f;
        float fnew = fmaf(alpha * res, flow_scale, flow);
        flow = fminf(fmaxf(fnew, 0.01f), 3.0f);
        if (use_hist && L.sub == 0) hist[(size_t)i * BATCH + L.elem] = flow;
    }
}

// ---------------------------------------------------------------------------
// Phase 1b: slots[b] = max over stage[b*NTHREADS .. +NTHREADS). Exact (max is
// order-independent) -> slots[] bit-identical to the atomic path.
// 1024 threads (launch_bounds MATCHES the launch — round-3 bug), float4
// strided loads, exactly in-bounds: 65536 floats = 16384 float4 = 16 iters.
// ---------------------------------------------------------------------------
__global__ __launch_bounds__(1024) void phase1b(const float* __restrict__ stage,
                                                float* __restrict__ slots) {
    const float4* src = (const float4*)(stage + (size_t)blockIdx.x * NTHREADS);
    float m = 0.0f;
#pragma unroll 4
    for (int k = threadIdx.x; k < NTHREADS / 4; k += 1024) {
        float4 v = src[k];
        m = fmaxf(m, fmaxf(fmaxf(v.x, v.y), fmaxf(v.z, v.w)));
    }
#pragma unroll
    for (int off = 32; off; off >>= 1) m = fmaxf(m, __shfl_xor(m, off));
    __shared__ float red[16];
    if ((threadIdx.x & 63) == 0) red[threadIdx.x >> 6] = m;
    __syncthreads();
    if (threadIdx.x == 0) {
        float v = red[0];
#pragma unroll
        for (int i = 1; i < 16; ++i) v = fmaxf(v, red[i]);
        slots[blockIdx.x] = v;
    }
}

// ---------------------------------------------------------------------------
// Phase 2+3 fused: replay stall/done automaton on slots, recover flow after k
// updates, compute outputs.
// ---------------------------------------------------------------------------
template <bool USE_HIST>
__global__ __launch_bounds__(256) void phase3(
        const float* __restrict__ fan_speed,
        const float* __restrict__ sup_pos, const float* __restrict__ exh_pos,
        const float* __restrict__ pa, const float* __restrict__ pb, const float* __restrict__ pc,
        const float* __restrict__ slr, const float* __restrict__ srl,
        const float* __restrict__ sdo, const float* __restrict__ sdk,
        const float* __restrict__ elr, const float* __restrict__ erl,
        const float* __restrict__ edo, const float* __restrict__ edk,
        const float* __restrict__ slots, const float* __restrict__ hist,
        float* __restrict__ out) {
    LaneConsts L = setup_lane(fan_speed, sup_pos, exh_pos, pa, pb, pc,
                              slr, srl, sdo, sdk, elr, erl, edo, edk);

    float prev = INFINITY;
    int stall = 0, k = NOUTER;
    bool done = false;
#pragma unroll 1
    for (int i = 0; i < NOUTER; ++i) {
        float err = slots[i];
        bool stalled = fabsf(err - prev) < 1e-6f;
        stall = stalled ? stall + 1 : 0;
        done = done || (err < 1e-3f) || (stall > 10);
        if (done) { k = i; break; }
        prev = err;
    }

    const float flow_scale = 2.0f / (500.0f + 1e-6f);
    float flow;
    if (USE_HIST) {
        flow = (k == 0) ? L.speed * 2.0f : hist[(size_t)(k - 1) * BATCH + L.elem];
    } else {
        flow = L.speed * 2.0f;
        float alpha_base = 0.5f;
#pragma unroll 1
        for (int i = 0; i < k; ++i) {
            float pfin;
            (void)distribute_lane(flow, L.R2, L.Rl, pfin);
            float sys = sys_from_p(pfin);
            float res = fan_pressure(flow, L.rspeed, L.speed2, L.a1000, L.b, L.c) - sys;
            float alpha = fmaxf(alpha_base, 0.05f);
            alpha_base *= 0.95f;
            float fnew = fmaf(alpha * res, flow_scale, flow);
            flow = fminf(fmaxf(fnew, 0.01f), 3.0f);
        }
    }

    flow = fmaxf(flow, 0.0f);
    float fanp = fan_pressure(flow, L.rspeed, L.speed2, L.a1000, L.b, L.c);

    float pfin;
    float ffin = distribute_lane(flow, L.R2, L.Rl, pfin);
    float sys  = sys_from_p(pfin);

    float fr  = flow * (1.0f / (2.0f + 1e-6f));
    float pr  = fanp * (1.0f / (500.0f + 1e-6f));
    float eta = 0.65f * (1.0f - 0.3f * (fr - 1.0f) * (fr - 1.0f)
                              - 0.2f * (pr - 1.0f) * (pr - 1.0f));
    eta = fminf(fmaxf(eta, 0.3f), 0.75f);
    float power = flow * fanp * fast_rcp(eta * 0.9f + 1e-6f);

    float* o = out + (size_t)L.elem * 20;
    if (L.sub == 0) {
        o[0] = flow; o[1] = fanp; o[2] = sys; o[3] = power;
    }
    int net = (L.sub >> 2) & 1;
    int j   = L.sub & 3;
    o[4 + net * 8 + j] = ffin;
    o[8 + net * 8 + j] = pfin;
}

// ---------------------------------------------------------------------------
extern "C" void kernel_launch(void* const* d_in, const int* in_sizes, int n_in,
                              void* d_out, int out_size, void* d_ws, size_t ws_size,
                              hipStream_t stream) {
    const float* fan_speed = (const float*)d_in[0];
    const float* sup_pos   = (const float*)d_in[1];
    const float* exh_pos   = (const float*)d_in[2];
    const float* pa        = (const float*)d_in[3];
    const float* pb        = (const float*)d_in[4];
    const float* pc        = (const float*)d_in[5];
    const float* slr       = (const float*)d_in[6];
    const float* srl       = (const float*)d_in[7];
    const float* sdo       = (const float*)d_in[8];
    const float* sdk       = (const float*)d_in[9];
    const float* elr       = (const float*)d_in[10];
    const float* erl       = (const float*)d_in[11];
    const float* edo       = (const float*)d_in[12];
    const float* edk       = (const float*)d_in[13];

    float* ws    = (float*)d_ws;
    float* slots = ws;                        // 64 floats
    float* hist  = ws + 64;                   // BATCH*NOUTER floats (1.6 MB)
    float* stage = ws + 64 + BATCH * NOUTER;  // NOUTER*NTHREADS floats (13.1 MB)

    size_t need_hist  = (size_t)(64 + BATCH * NOUTER) * sizeof(float);
    size_t need_stage = need_hist + (size_t)NOUTER * NTHREADS * sizeof(float);
    bool use_hist  = ws_size >= need_hist;
    bool use_stage = ws_size >= need_stage;

    dim3 grid(NTHREADS / 256), block(256);

    phase1<<<grid, block, 0, stream>>>(fan_speed, sup_pos, exh_pos, pa, pb, pc,
                                       slr, srl, sdo, sdk, elr, erl, edo, edk,
                                       slots, hist, use_stage ? stage : nullptr,
                                       use_hist ? 1 : 0);
    if (use_stage)
        phase1b<<<dim3(NOUTER), dim3(1024), 0, stream>>>(stage, slots);

    if (use_hist) {
        phase3<true><<<grid, block, 0, stream>>>(fan_speed, sup_pos, exh_pos, pa, pb, pc,
                                                 slr, srl, sdo, sdk, elr, erl, edo, edk,
                                                 slots, hist, (float*)d_out);
    } else {
        phase3<false><<<grid, block, 0, stream>>>(fan_speed, sup_pos, exh_pos, pa, pb, pc,
                                                  slr, srl, sdo, sdk, elr, erl, edo, edk,
                                                  slots, nullptr, (float*)d_out);
    }
}

// Round 6
// 133.994 us; speedup vs baseline: 5.5021x; 1.0305x over previous
//
#include <hip/hip_runtime.h>
#include <math.h>

#define BATCH   8192
#define NOUTER  50
#define NINNER  15
#define NTHREADS (BATCH * 8)   // 8 lanes per element: net(2) x branch(4)
#define NWAVES  (NTHREADS / 64)  // 1024

__device__ __forceinline__ float fast_rcp(float x)  { return __builtin_amdgcn_rcpf(x); }
__device__ __forceinline__ float fast_sqrt(float x) { return __builtin_amdgcn_sqrtf(x); }

// DPP cross-lane move (VALU pipe). quad_perm = sel0|sel1<<2|sel2<<4|sel3<<6
template <int CTRL>
__device__ __forceinline__ float dpp_movf(float x) {
    return __int_as_float(__builtin_amdgcn_update_dpp(
        0, __float_as_int(x), CTRL, 0xF, 0xF, true));
}
#define DPP_XOR1  0xB1   // quad_perm [1,0,3,2]
#define DPP_XOR2  0x4E   // quad_perm [2,3,0,1]
#define DPP_BQ0   0x00   // quad_perm [0,0,0,0] : broadcast quad lane 0
#define DPP_ROR8  0x128  // row_ror:8  == xor8 within 16-lane row (on 8-uniform data)
#define DPP_HMIR  0x141  // row_half_mirror == xor7 (== xor4 on quad-uniform data)
#define DPP_BC15  0x142  // row_bcast15: lanes 16-31 <- lane15, 48-63 <- lane47 (others 0)
#define DPP_BC31  0x143  // row_bcast31: lanes 32-63 <- lane31 (others 0)

// ---------------------------------------------------------------------------
// Lane-parallel flow distribution. Each lane owns ONE branch. Cross-branch
// sums via quad_perm DPP. Bit-identical math to rounds 2-5.
// ---------------------------------------------------------------------------
__device__ __forceinline__ float distribute_lane(float total, float R2, float Rl,
                                                 float& pout) {
    float f = total * 0.25f;
#pragma unroll
    for (int it = 0; it < NINNER; ++it) {
        float p  = fmaf(R2, f * f, Rl * f);          // f >= 0 -> |f| == f
        float t  = p + dpp_movf<DPP_XOR1>(p);
        t       += dpp_movf<DPP_XOR2>(t);
        float target = t * 0.25f;
        float q2e = fmaf(f, f, 1e-6f);
        float den = fmaf(q2e, 1e-6f, p);
        float ratio = target * q2e * fast_rcp(den);  // >= 0 by construction
        float nw = fast_sqrt(ratio);
        float s  = nw + dpp_movf<DPP_XOR1>(nw);
        s       += dpp_movf<DPP_XOR2>(s);
        f = nw * total * fast_rcp(s + 1e-6f);
    }
    pout = fmaf(R2, f * f, Rl * f);
    return f;
}

__device__ __forceinline__ float fan_pressure(float flow, float rspeed, float speed2,
                                              float a1000, float b, float c) {
    float fn = flow * rspeed;
    float pd = fmaf(c, fn * fn, fmaf(b, fn, a1000));
    return fmaxf(pd * speed2, 0.0f);
}

// sys pressure = p0(sup) + p0(exh), broadcast to all 8 lanes of the element.
__device__ __forceinline__ float sys_from_p(float pfin) {
    float p0 = dpp_movf<DPP_BQ0>(pfin);
    return p0 + dpp_movf<DPP_HMIR>(p0);
}

struct LaneConsts {
    float R2, Rl;
    float speed, rspeed, speed2, a1000, b, c;
    int elem, lane, sub;
};

__device__ __forceinline__ LaneConsts setup_lane(
        const float* fan_speed,
        const float* sup_pos, const float* exh_pos,
        const float* pa, const float* pb, const float* pc,
        const float* slr, const float* srl, const float* sdo, const float* sdk,
        const float* elr, const float* erl, const float* edo, const float* edk) {
    LaneConsts L;
    int t   = blockIdx.x * blockDim.x + threadIdx.x;
    L.elem  = t >> 3;
    L.sub   = t & 7;
    int net = (L.sub >> 2) & 1;
    int j   = L.sub & 3;
    L.lane  = threadIdx.x & 63;

    const float* pos = net ? exh_pos : sup_pos;
    const float* lr  = net ? elr : slr;
    const float* rl  = net ? erl : srl;
    const float* dlo = net ? edo : sdo;
    const float* dk  = net ? edk : sdk;

    float Rduct = expf(lr[j]);
    float Rd    = expf(dlo[j]) * expf(dk[j] * (1.0f - pos[L.elem * 4 + j]));
    L.R2 = Rduct + Rd;
    L.Rl = fabsf(rl[j]);

    L.speed  = fan_speed[L.elem];
    L.rspeed = fast_rcp(L.speed + 1e-6f);
    L.speed2 = L.speed * L.speed;
    L.a1000  = pa[0] * 1000.0f;
    L.b      = pb[0];
    L.c      = pc[0];
    return L;
}

// ---------------------------------------------------------------------------
// Phase 1: all 50 outer iterations ungated.
//   stage != nullptr : pure-VALU DPP wave64 max-reduce of |res| (ror8 +
//                      row_bcast15 + row_bcast31; valid: ares >= 0 and
//                      bound_ctrl zero-fills non-target lanes), lane 63
//                      stores ONE float per wave per iter. No atomics, no DS
//                      ops, store off the dependency chain. 200 KB total.
//   stage == nullptr : fallback: wave max-reduce + atomicMax (round-2 path).
// ---------------------------------------------------------------------------
__global__ __launch_bounds__(256) void phase1(
        const float* __restrict__ fan_speed,
        const float* __restrict__ sup_pos, const float* __restrict__ exh_pos,
        const float* __restrict__ pa, const float* __restrict__ pb, const float* __restrict__ pc,
        const float* __restrict__ slr, const float* __restrict__ srl,
        const float* __restrict__ sdo, const float* __restrict__ sdk,
        const float* __restrict__ elr, const float* __restrict__ erl,
        const float* __restrict__ edo, const float* __restrict__ edk,
        float* __restrict__ slots, float* __restrict__ hist,
        float* __restrict__ stage, int use_hist) {
    LaneConsts L = setup_lane(fan_speed, sup_pos, exh_pos, pa, pb, pc,
                              slr, srl, sdo, sdk, elr, erl, edo, edk);
    int t = blockIdx.x * blockDim.x + threadIdx.x;
    int wave = t >> 6;
    const float flow_scale = 2.0f / (500.0f + 1e-6f);
    float flow = L.speed * 2.0f;
    float alpha_base = 0.5f;

#pragma unroll 1
    for (int i = 0; i < NOUTER; ++i) {
        float pfin;
        (void)distribute_lane(flow, L.R2, L.Rl, pfin);
        float sys  = sys_from_p(pfin);
        float res  = fan_pressure(flow, L.rspeed, L.speed2, L.a1000, L.b, L.c) - sys;
        float ares = fabsf(res);

        if (stage) {
            // ares is uniform per 8-lane element group.
            float m = fmaxf(ares, dpp_movf<DPP_ROR8>(ares)); // row(16)-uniform
            m = fmaxf(m, dpp_movf<DPP_BC15>(m));  // lanes16-31:max(r0,r1); 48-63:max(r2,r3)
            m = fmaxf(m, dpp_movf<DPP_BC31>(m));  // lane 63: global wave max
            if (L.lane == 63)
                stage[i * NWAVES + wave] = m;     // 1 store/wave/iter, off-chain
        } else {
            float m = ares;
            m = fmaxf(m, dpp_movf<DPP_ROR8>(m));
            m = fmaxf(m, __shfl_xor(m, 16));
            m = fmaxf(m, __shfl_xor(m, 32));
            if (L.lane == 0)
                atomicMax((int*)&slots[i], __float_as_int(m));
        }

        float alpha = fmaxf(alpha_base, 0.05f);
        alpha_base *= 0.95f;
        float fnew = fmaf(alpha * res, flow_scale, flow);
        flow = fminf(fmaxf(fnew, 0.01f), 3.0f);
        if (use_hist && L.sub == 0) hist[(size_t)i * BATCH + L.elem] = flow;
    }
}

// ---------------------------------------------------------------------------
// Phase 1b: single block. Reduce 1024 wave-maxes per slot (exact, order-
// independent -> bit-identical slots), then run the stall/done automaton
// once and write k.
// ---------------------------------------------------------------------------
__global__ __launch_bounds__(1024) void phase1b(const float* __restrict__ stage,
                                                int* __restrict__ kout) {
    __shared__ float sl[NOUTER];
    int lane = threadIdx.x & 63;
    int wv   = threadIdx.x >> 6;   // 0..15
#pragma unroll 1
    for (int i = wv; i < NOUTER; i += 16) {
        const float4* src = (const float4*)(stage + (size_t)i * NWAVES);
        float m = 0.0f;
#pragma unroll
        for (int q = 0; q < 4; ++q) {             // 256 float4 = 1024 floats
            float4 v = src[lane + 64 * q];
            m = fmaxf(m, fmaxf(fmaxf(v.x, v.y), fmaxf(v.z, v.w)));
        }
#pragma unroll
        for (int off = 32; off; off >>= 1) m = fmaxf(m, __shfl_xor(m, off));
        if (lane == 0) sl[i] = m;
    }
    __syncthreads();
    if (threadIdx.x == 0) {
        float prev = INFINITY;
        int stall = 0, k = NOUTER;
        bool done = false;
#pragma unroll 1
        for (int i = 0; i < NOUTER; ++i) {
            float err = sl[i];
            bool stalled = fabsf(err - prev) < 1e-6f;
            stall = stalled ? stall + 1 : 0;
            done = done || (err < 1e-3f) || (stall > 10);
            if (done) { k = i; break; }
            prev = err;
        }
        *kout = k;
    }
}

// ---------------------------------------------------------------------------
// Phase 3: get k (from kptr, or replay automaton on slots in fallback),
// recover flow after k updates, compute outputs.
// ---------------------------------------------------------------------------
template <bool USE_HIST>
__global__ __launch_bounds__(256) void phase3(
        const float* __restrict__ fan_speed,
        const float* __restrict__ sup_pos, const float* __restrict__ exh_pos,
        const float* __restrict__ pa, const float* __restrict__ pb, const float* __restrict__ pc,
        const float* __restrict__ slr, const float* __restrict__ srl,
        const float* __restrict__ sdo, const float* __restrict__ sdk,
        const float* __restrict__ elr, const float* __restrict__ erl,
        const float* __restrict__ edo, const float* __restrict__ edk,
        const float* __restrict__ slots, const int* __restrict__ kin, int use_k,
        const float* __restrict__ hist, float* __restrict__ out) {
    LaneConsts L = setup_lane(fan_speed, sup_pos, exh_pos, pa, pb, pc,
                              slr, srl, sdo, sdk, elr, erl, edo, edk);

    int k;
    if (use_k) {
        k = *kin;                      // uniform scalar load, automaton pre-run
    } else {
        float prev = INFINITY;
        int stall = 0; k = NOUTER;
        bool done = false;
#pragma unroll 1
        for (int i = 0; i < NOUTER; ++i) {
            float err = slots[i];
            bool stalled = fabsf(err - prev) < 1e-6f;
            stall = stalled ? stall + 1 : 0;
            done = done || (err < 1e-3f) || (stall > 10);
            if (done) { k = i; break; }
            prev = err;
        }
    }

    const float flow_scale = 2.0f / (500.0f + 1e-6f);
    float flow;
    if (USE_HIST) {
        flow = (k == 0) ? L.speed * 2.0f : hist[(size_t)(k - 1) * BATCH + L.elem];
    } else {
        flow = L.speed * 2.0f;
        float alpha_base = 0.5f;
#pragma unroll 1
        for (int i = 0; i < k; ++i) {
            float pfin;
            (void)distribute_lane(flow, L.R2, L.Rl, pfin);
            float sys = sys_from_p(pfin);
            float res = fan_pressure(flow, L.rspeed, L.speed2, L.a1000, L.b, L.c) - sys;
            float alpha = fmaxf(alpha_base, 0.05f);
            alpha_base *= 0.95f;
            float fnew = fmaf(alpha * res, flow_scale, flow);
            flow = fminf(fmaxf(fnew, 0.01f), 3.0f);
        }
    }

    flow = fmaxf(flow, 0.0f);
    float fanp = fan_pressure(flow, L.rspeed, L.speed2, L.a1000, L.b, L.c);

    float pfin;
    float ffin = distribute_lane(flow, L.R2, L.Rl, pfin);
    float sys  = sys_from_p(pfin);

    float fr  = flow * (1.0f / (2.0f + 1e-6f));
    float pr  = fanp * (1.0f / (500.0f + 1e-6f));
    float eta = 0.65f * (1.0f - 0.3f * (fr - 1.0f) * (fr - 1.0f)
                              - 0.2f * (pr - 1.0f) * (pr - 1.0f));
    eta = fminf(fmaxf(eta, 0.3f), 0.75f);
    float power = flow * fanp * fast_rcp(eta * 0.9f + 1e-6f);

    float* o = out + (size_t)L.elem * 20;
    if (L.sub == 0) {
        o[0] = flow; o[1] = fanp; o[2] = sys; o[3] = power;
    }
    int net = (L.sub >> 2) & 1;
    int j   = L.sub & 3;
    o[4 + net * 8 + j] = ffin;
    o[8 + net * 8 + j] = pfin;
}

// ---------------------------------------------------------------------------
extern "C" void kernel_launch(void* const* d_in, const int* in_sizes, int n_in,
                              void* d_out, int out_size, void* d_ws, size_t ws_size,
                              hipStream_t stream) {
    const float* fan_speed = (const float*)d_in[0];
    const float* sup_pos   = (const float*)d_in[1];
    const float* exh_pos   = (const float*)d_in[2];
    const float* pa        = (const float*)d_in[3];
    const float* pb        = (const float*)d_in[4];
    const float* pc        = (const float*)d_in[5];
    const float* slr       = (const float*)d_in[6];
    const float* srl       = (const float*)d_in[7];
    const float* sdo       = (const float*)d_in[8];
    const float* sdk       = (const float*)d_in[9];
    const float* elr       = (const float*)d_in[10];
    const float* erl       = (const float*)d_in[11];
    const float* edo       = (const float*)d_in[12];
    const float* edk       = (const float*)d_in[13];

    float* ws    = (float*)d_ws;
    float* slots = ws;                         // 64 floats (fallback path)
    int*   kptr  = (int*)(ws + 64);            // 1 int
    float* hist  = ws + 128;                   // BATCH*NOUTER floats (1.6 MB)
    float* stage = ws + 128 + BATCH * NOUTER;  // NOUTER*NWAVES floats (200 KB)

    size_t need_hist  = (size_t)(128 + BATCH * NOUTER) * sizeof(float);
    size_t need_stage = need_hist + (size_t)NOUTER * NWAVES * sizeof(float);
    bool use_hist  = ws_size >= need_hist;
    bool use_stage = ws_size >= need_stage;

    dim3 grid(NTHREADS / 256), block(256);

    phase1<<<grid, block, 0, stream>>>(fan_speed, sup_pos, exh_pos, pa, pb, pc,
                                       slr, srl, sdo, sdk, elr, erl, edo, edk,
                                       slots, hist, use_stage ? stage : nullptr,
                                       use_hist ? 1 : 0);
    if (use_stage)
        phase1b<<<dim3(1), dim3(1024), 0, stream>>>(stage, kptr);

    if (use_hist) {
        phase3<true><<<grid, block, 0, stream>>>(fan_speed, sup_pos, exh_pos, pa, pb, pc,
                                                 slr, srl, sdo, sdk, elr, erl, edo, edk,
                                                 slots, kptr, use_stage ? 1 : 0,
                                                 hist, (float*)d_out);
    } else {
        phase3<false><<<grid, block, 0, stream>>>(fan_speed, sup_pos, exh_pos, pa, pb, pc,
                                                  slr, srl, sdo, sdk, elr, erl, edo, edk,
                                                  slots, kptr, use_stage ? 1 : 0,
                                                  nullptr, (float*)d_out);
    }
}